// Round 9
// baseline (1459.977 us; speedup 1.0000x reference)
//
#include <hip/hip_runtime.h>
#include <math.h>

#define B_   16
#define T_   3072
#define D_   256
#define G_   1024
#define BT_  (B_*T_)            // 49152
#define RPB  16                 // rows per block (acc[16][4] = 64 VGPR)
#define NCAND 16                // max refine candidates per row
#define MARGIN 0.05f            // fp32 d2 ambiguity margin (~50x worst-case fp32 err)

// output layout (float elements)
#define OFF_SOMZ 0ULL
#define OFF_Q    12582912ULL
#define OFF_BMU  62914560ULL
#define OFF_KC   62963712ULL

// ---------------- kernel A: transpose nodes + per-node ||n||^2 (perf path only) ----------------
__global__ __launch_bounds__(256) void prep_nodes(const float* __restrict__ nodes,
                                                  float* __restrict__ nT,
                                                  float* __restrict__ nsq) {
    int c = blockIdx.x;       // 0..1023
    int k = threadIdx.x;      // 0..255
    float v = nodes[c * D_ + k];
    nT[k * G_ + c] = v;
    float s = v * v;
    #pragma unroll
    for (int m = 32; m; m >>= 1) s += __shfl_xor(s, m, 64);
    __shared__ float ws4[4];
    if ((threadIdx.x & 63) == 0) ws4[threadIdx.x >> 6] = s;
    __syncthreads();
    if (threadIdx.x == 0) nsq[c] = ws4[0] + ws4[1] + ws4[2] + ws4[3];
}

// ---------------- kernel B: fused GEMM + softassign + f64-refined argmin + som_z ----------------
template <bool USE_NT>
__global__ __launch_bounds__(256, 4) void som_main(const float* __restrict__ z,
                                                   const float* __restrict__ mask,
                                                   const float* __restrict__ nodes,
                                                   const float* __restrict__ nT,
                                                   const float* __restrict__ nsq,
                                                   float* __restrict__ out) {
    __shared__ __align__(16) float zl[RPB][D_];   // weighted z tile (16 KB)
    __shared__ float zsq_s[RPB];
    __shared__ float mk_s[RPB];
    __shared__ float tw_s[RPB];
    __shared__ int   bmu_s[RPB];
    __shared__ float qinv_s[RPB];
    __shared__ float dmin2_s[RPB];
    __shared__ int   cnt_s[RPB];
    __shared__ int   cand_s[RPB][NCAND];
    __shared__ unsigned long long mred[RPB][4];
    __shared__ float qred[RPB][4];

    const int tid  = threadIdx.x;
    const int lane = tid & 63;
    const int wave = tid >> 6;
    const int row0 = blockIdx.x * RPB;          // global flat row base (b*T + t)
    const int b    = row0 / T_;                 // 3072 % 16 == 0 -> block within one b
    const int t0   = row0 % T_;

    // ---- per-row tw/mask tables (16 pow calls per block, not 2048) ----
    if (tid < RPB) {
        int t = t0 + tid;
        mk_s[tid] = mask[b * T_ + t];
        tw_s[tid] = (float)pow((double)0.999f, (double)(T_ - 1 - t));  // f32-CR power
        cnt_s[tid] = 0;
    }
    __syncthreads();

    // ---- stage weighted z into LDS (wz = fl(fl(z*tw)*mask)) ----
    const float4* z4  = (const float4*)(z + (size_t)row0 * D_);
    float4* zl4 = (float4*)zl;
    #pragma unroll
    for (int i = 0; i < 4; ++i) {
        int p = i * 256 + tid;          // float4 index within tile [0,1024)
        int r = p >> 6;                 // row handled by this wave this step
        float tw = tw_s[r];
        float m  = mk_s[r];
        float4 v = z4[p];
        v.x = __fmul_rn(__fmul_rn(v.x, tw), m);
        v.y = __fmul_rn(__fmul_rn(v.y, tw), m);
        v.z = __fmul_rn(__fmul_rn(v.z, tw), m);
        v.w = __fmul_rn(__fmul_rn(v.w, tw), m);
        zl4[p] = v;
        float s = v.x*v.x + v.y*v.y + v.z*v.z + v.w*v.w;
        #pragma unroll
        for (int mm = 32; mm; mm >>= 1) s += __shfl_xor(s, mm, 64);
        if (lane == 0) zsq_s[r] = s;
    }
    __syncthreads();

    // ---- main GEMM: acc[r][j] = dot(wz_row_r, node_col(4*tid+j)) ----
    float acc[RPB][4];
    #pragma unroll
    for (int r = 0; r < RPB; ++r)
        #pragma unroll
        for (int j = 0; j < 4; ++j) acc[r][j] = 0.f;

    float nss[4] = {0.f, 0.f, 0.f, 0.f};          // fallback: ||n_c||^2 on the fly
    const float4* nT4 = (const float4*)nT;        // nT4[k*256 + t] = n[k][4t..4t+3]
    const float4* nd4 = (const float4*)nodes;     // nd4[c*64 + k4]  = n[c][4k..4k+3]

    for (int k4 = 0; k4 < 64; ++k4) {
        if constexpr (USE_NT) {
            float4 nv0 = nT4[(k4*4 + 0) * 256 + tid];
            float4 nv1 = nT4[(k4*4 + 1) * 256 + tid];
            float4 nv2 = nT4[(k4*4 + 2) * 256 + tid];
            float4 nv3 = nT4[(k4*4 + 3) * 256 + tid];
            #pragma unroll
            for (int r = 0; r < RPB; ++r) {
                float4 zv = zl4[r * 64 + k4];     // broadcast across lanes
                acc[r][0] = fmaf(zv.x, nv0.x, acc[r][0]);
                acc[r][1] = fmaf(zv.x, nv0.y, acc[r][1]);
                acc[r][2] = fmaf(zv.x, nv0.z, acc[r][2]);
                acc[r][3] = fmaf(zv.x, nv0.w, acc[r][3]);
                acc[r][0] = fmaf(zv.y, nv1.x, acc[r][0]);
                acc[r][1] = fmaf(zv.y, nv1.y, acc[r][1]);
                acc[r][2] = fmaf(zv.y, nv1.z, acc[r][2]);
                acc[r][3] = fmaf(zv.y, nv1.w, acc[r][3]);
                acc[r][0] = fmaf(zv.z, nv2.x, acc[r][0]);
                acc[r][1] = fmaf(zv.z, nv2.y, acc[r][1]);
                acc[r][2] = fmaf(zv.z, nv2.z, acc[r][2]);
                acc[r][3] = fmaf(zv.z, nv2.w, acc[r][3]);
                acc[r][0] = fmaf(zv.w, nv3.x, acc[r][0]);
                acc[r][1] = fmaf(zv.w, nv3.y, acc[r][1]);
                acc[r][2] = fmaf(zv.w, nv3.z, acc[r][2]);
                acc[r][3] = fmaf(zv.w, nv3.w, acc[r][3]);
            }
        } else {
            float4 c0 = nd4[(4*tid + 0) * 64 + k4];
            float4 c1 = nd4[(4*tid + 1) * 64 + k4];
            float4 c2 = nd4[(4*tid + 2) * 64 + k4];
            float4 c3 = nd4[(4*tid + 3) * 64 + k4];
            nss[0] += c0.x*c0.x + c0.y*c0.y + c0.z*c0.z + c0.w*c0.w;
            nss[1] += c1.x*c1.x + c1.y*c1.y + c1.z*c1.z + c1.w*c1.w;
            nss[2] += c2.x*c2.x + c2.y*c2.y + c2.z*c2.z + c2.w*c2.w;
            nss[3] += c3.x*c3.x + c3.y*c3.y + c3.z*c3.z + c3.w*c3.w;
            #pragma unroll
            for (int r = 0; r < RPB; ++r) {
                float4 zv = zl4[r * 64 + k4];
                acc[r][0] = fmaf(zv.x, c0.x, fmaf(zv.y, c0.y, fmaf(zv.z, c0.z, fmaf(zv.w, c0.w, acc[r][0]))));
                acc[r][1] = fmaf(zv.x, c1.x, fmaf(zv.y, c1.y, fmaf(zv.z, c1.z, fmaf(zv.w, c1.w, acc[r][1]))));
                acc[r][2] = fmaf(zv.x, c2.x, fmaf(zv.y, c2.y, fmaf(zv.z, c2.z, fmaf(zv.w, c2.w, acc[r][2]))));
                acc[r][3] = fmaf(zv.x, c3.x, fmaf(zv.y, c3.y, fmaf(zv.z, c3.z, fmaf(zv.w, c3.w, acc[r][3]))));
            }
        }
    }

    // ---- epilogue: dist, q, per-row sum + fp32 argmin (top-1) ----
    float nsq_loc[4];
    if constexpr (USE_NT) {
        float4 nv = ((const float4*)nsq)[tid];
        nsq_loc[0] = nv.x; nsq_loc[1] = nv.y; nsq_loc[2] = nv.z; nsq_loc[3] = nv.w;
    } else {
        nsq_loc[0] = nss[0]; nsq_loc[1] = nss[1]; nsq_loc[2] = nss[2]; nsq_loc[3] = nss[3];
    }

    #pragma unroll
    for (int r = 0; r < RPB; ++r) {
        float zq = zsq_s[r];
        float qs = 0.f;
        unsigned long long mn1 = ~0ULL;
        #pragma unroll
        for (int j = 0; j < 4; ++j) {
            float d2   = zq - 2.f * acc[r][j] + nsq_loc[j];
            float dist = sqrtf(fmaxf(d2, 1e-12f));
            float qu   = 1.f / (1.f + dist);
            acc[r][j]  = qu;                      // keep qu; d2 recoverable via 1/qu-1
            qs += qu;
            unsigned long long pk =
                ((unsigned long long)__float_as_uint(dist) << 32) | (unsigned)(4*tid + j);
            mn1 = pk < mn1 ? pk : mn1;
        }
        #pragma unroll
        for (int mm = 32; mm; mm >>= 1) {
            qs += __shfl_xor(qs, mm, 64);
            unsigned long long o1 = __shfl_xor(mn1, mm, 64);
            mn1 = o1 < mn1 ? o1 : mn1;
        }
        if (lane == 0) { qred[r][wave] = qs; mred[r][wave] = mn1; }
    }
    __syncthreads();

    if (tid < RPB) {
        int r = tid;
        float qs = qred[r][0] + qred[r][1] + qred[r][2] + qred[r][3];
        unsigned long long mn1 = mred[r][0];
        mn1 = mred[r][1] < mn1 ? mred[r][1] : mn1;
        mn1 = mred[r][2] < mn1 ? mred[r][2] : mn1;
        mn1 = mred[r][3] < mn1 ? mred[r][3] : mn1;
        float dmin = __uint_as_float((unsigned)(mn1 >> 32));
        dmin2_s[r] = dmin * dmin;
        qinv_s[r]  = 1.f / qs;
    }
    __syncthreads();

    // ---- candidate gather: every node within MARGIN of the row's fp32 min d2 ----
    #pragma unroll
    for (int r = 0; r < RPB; ++r) {
        float lim = dmin2_s[r] + MARGIN;
        #pragma unroll
        for (int j = 0; j < 4; ++j) {
            float dist_rec = 1.f / acc[r][j] - 1.f;      // invert qu -> dist
            float d2r = dist_rec * dist_rec;
            if (d2r < lim) {
                int slot = atomicAdd(&cnt_s[r], 1);
                if (slot < NCAND) cand_s[r][slot] = 4 * tid + j;
            }
        }
    }

    // ---- q writeback (normalized); acc dies here, before the f64 section ----
    float4* q4 = (float4*)(out + OFF_Q + (size_t)row0 * G_);
    #pragma unroll
    for (int r = 0; r < RPB; ++r) {
        float qi = qinv_s[r];
        float4 v;
        v.x = acc[r][0] * qi; v.y = acc[r][1] * qi;
        v.z = acc[r][2] * qi; v.w = acc[r][3] * qi;
        q4[r * 256 + tid] = v;
    }
    __syncthreads();

    // ---- f64 re-rank of the candidate set (np-f64 reference emulation) ----
    // wz64 = f64(z)*f64(tw32)*f64(mask); compare s_c = nsq_c - 2*dot_c (zsq common);
    // tie -> lowest index. 16 threads per row.
    {
        const int r = tid >> 4;          // 0..15
        const int s = tid & 15;
        const int cnt = cnt_s[r] < NCAND ? cnt_s[r] : NCAND;
        const int row = row0 + r;
        const double w64 = (double)tw_s[r] * (double)mk_s[r];
        const float* zp = z + (size_t)row * D_;
        double bs = 1e300; int bc = 0x7FFFFFFF;
        for (int i = s; i < cnt; i += 16) {
            const int c = cand_s[r][i];
            const float* nc = nodes + (size_t)c * D_;
            double dot = 0.0, nsqd = 0.0;
            for (int k = 0; k < D_; ++k) {
                double zw = (double)zp[k] * w64;
                double nv = (double)nc[k];
                dot  = fma(zw, nv, dot);
                nsqd = fma(nv, nv, nsqd);
            }
            double sc = nsqd - 2.0 * dot;
            if (sc < bs || (sc == bs && c < bc)) { bs = sc; bc = c; }
        }
        #pragma unroll
        for (int mm = 1; mm < 16; mm <<= 1) {
            double os = __shfl_xor(bs, mm, 64);
            int    oc = __shfl_xor(bc, mm, 64);
            if (os < bs || (os == bs && oc < bc)) { bs = os; bc = oc; }
        }
        if (s == 0) {
            bmu_s[r] = bc;
            out[OFF_BMU + row]       = (float)bc;
            out[OFF_KC + 2*row]      = (float)(bc >> 5);
            out[OFF_KC + 2*row + 1]  = (float)(bc & 31);
        }
    }
    __syncthreads();

    // ---- som_z = z + 0.1*(nodes[bmu] - z)*mask ----
    const float4* zr4 = (const float4*)(z + (size_t)row0 * D_);
    float4* so4 = (float4*)(out + OFF_SOMZ + (size_t)row0 * D_);
    #pragma unroll
    for (int i = 0; i < 4; ++i) {
        int p  = i * 256 + tid;
        int r  = p >> 6;
        int k4 = p & 63;
        float4 zv = zr4[p];
        float4 nn = ((const float4*)(nodes + (size_t)bmu_s[r] * D_))[k4];
        float m = 0.1f * mk_s[r];
        float4 o;
        o.x = zv.x + m * (nn.x - zv.x);
        o.y = zv.y + m * (nn.y - zv.y);
        o.z = zv.z + m * (nn.z - zv.z);
        o.w = zv.w + m * (nn.w - zv.w);
        so4[p] = o;
    }
}

extern "C" void kernel_launch(void* const* d_in, const int* in_sizes, int n_in,
                              void* d_out, int out_size, void* d_ws, size_t ws_size,
                              hipStream_t stream) {
    const float* z     = (const float*)d_in[0];
    const float* mask  = (const float*)d_in[1];
    const float* nodes = (const float*)d_in[2];
    float* out = (float*)d_out;

    const size_t need = (size_t)(D_ * G_ + G_) * sizeof(float);  // nT + nsq (~1.05 MB)
    if (ws_size >= need) {
        float* nT  = (float*)d_ws;
        float* nsq = nT + (size_t)D_ * G_;
        prep_nodes<<<G_, 256, 0, stream>>>(nodes, nT, nsq);
        som_main<true><<<BT_ / RPB, 256, 0, stream>>>(z, mask, nodes, nT, nsq, out);
    } else {
        som_main<false><<<BT_ / RPB, 256, 0, stream>>>(z, mask, nodes, nullptr, nullptr, out);
    }
}

// Round 10
// 418.408 us; speedup vs baseline: 3.4894x; 3.4894x over previous
//
#include <hip/hip_runtime.h>
#include <math.h>

#define B_   16
#define T_   3072
#define D_   256
#define G_   1024
#define BT_  (B_*T_)            // 49152
#define RPB  16                 // rows per block
#define NCAND 16                // max refine candidates per row
#define MARGIN 0.05f            // fp32 d2 ambiguity margin (~50x worst-case fp32 err)

// output layout (float elements)
#define OFF_SOMZ 0ULL
#define OFF_Q    12582912ULL
#define OFF_BMU  62914560ULL
#define OFF_KC   62963712ULL

#define ROWS16(M) M(0) M(1) M(2) M(3) M(4) M(5) M(6) M(7) \
                  M(8) M(9) M(10) M(11) M(12) M(13) M(14) M(15)

// ---------------- kernel A: transpose nodes + per-node ||n||^2 (perf path only) ----------------
__global__ __launch_bounds__(256) void prep_nodes(const float* __restrict__ nodes,
                                                  float* __restrict__ nT,
                                                  float* __restrict__ nsq) {
    int c = blockIdx.x;       // 0..1023
    int k = threadIdx.x;      // 0..255
    float v = nodes[c * D_ + k];
    nT[k * G_ + c] = v;
    float s = v * v;
    #pragma unroll
    for (int m = 32; m; m >>= 1) s += __shfl_xor(s, m, 64);
    __shared__ float ws4[4];
    if ((threadIdx.x & 63) == 0) ws4[threadIdx.x >> 6] = s;
    __syncthreads();
    if (threadIdx.x == 0) nsq[c] = ws4[0] + ws4[1] + ws4[2] + ws4[3];
}

__device__ __forceinline__ void argmin_upd(unsigned long long& mn, float dist, int col) {
    unsigned long long pk = ((unsigned long long)__float_as_uint(dist) << 32) | (unsigned)col;
    mn = pk < mn ? pk : mn;
}
__device__ __forceinline__ float qcomp(float zq, float dot, float nsq,
                                       unsigned long long& mn, int col) {
    float d2   = zq - 2.f * dot + nsq;
    float dist = sqrtf(fmaxf(d2, 1e-12f));
    argmin_upd(mn, dist, col);
    return 1.f / (1.f + dist);
}

// ---------------- kernel B: fused GEMM + softassign + f64-refined argmin + som_z ----------------
// NO __launch_bounds__: live set ~90 VGPR; let the allocator breathe (rounds 8/9: any
// cap made it keep acc and spill temps -> GBs of scratch traffic).
template <bool USE_NT>
__global__ void som_main(const float* __restrict__ z,
                         const float* __restrict__ mask,
                         const float* __restrict__ nodes,
                         const float* __restrict__ nT,
                         const float* __restrict__ nsq,
                         float* __restrict__ out) {
    __shared__ __align__(16) float zl[RPB][D_];   // weighted z tile (16 KB)
    __shared__ float zsq_s[RPB];
    __shared__ float mk_s[RPB];
    __shared__ float tw_s[RPB];
    __shared__ int   bmu_s[RPB];
    __shared__ float qinv_s[RPB];
    __shared__ float dmin2_s[RPB];
    __shared__ int   cnt_s[RPB];
    __shared__ int   cand_s[RPB][NCAND];
    __shared__ unsigned long long mred[RPB][4];
    __shared__ float qred[RPB][4];

    const int tid  = threadIdx.x;
    const int lane = tid & 63;
    const int wave = tid >> 6;
    const int row0 = blockIdx.x * RPB;          // global flat row base (b*T + t)
    const int b    = row0 / T_;                 // 3072 % 16 == 0 -> block within one b
    const int t0   = row0 % T_;

    // ---- per-row tw/mask tables (16 pow calls per block) ----
    if (tid < RPB) {
        int t = t0 + tid;
        mk_s[tid] = mask[b * T_ + t];
        tw_s[tid] = (float)pow((double)0.999f, (double)(T_ - 1 - t));  // f32-CR power
        cnt_s[tid] = 0;
    }
    __syncthreads();

    // ---- stage weighted z into LDS (wz = fl(fl(z*tw)*mask)) ----
    const float4* z4  = (const float4*)(z + (size_t)row0 * D_);
    float4* zl4 = (float4*)zl;
    #pragma unroll
    for (int i = 0; i < 4; ++i) {
        int p = i * 256 + tid;          // float4 index within tile [0,1024)
        int r = p >> 6;                 // row handled by this wave this step
        float tw = tw_s[r];
        float m  = mk_s[r];
        float4 v = z4[p];
        v.x = __fmul_rn(__fmul_rn(v.x, tw), m);
        v.y = __fmul_rn(__fmul_rn(v.y, tw), m);
        v.z = __fmul_rn(__fmul_rn(v.z, tw), m);
        v.w = __fmul_rn(__fmul_rn(v.w, tw), m);
        zl4[p] = v;
        float s = v.x*v.x + v.y*v.y + v.z*v.z + v.w*v.w;
        #pragma unroll
        for (int mm = 32; mm; mm >>= 1) s += __shfl_xor(s, mm, 64);
        if (lane == 0) zsq_s[r] = s;
    }
    __syncthreads();

    // ---- main GEMM: a<r>[j] = dot(wz_row_r, node_col(4*tid+j)) ----
    // Named float4 accumulators: no array => nothing for the allocator to demote.
#define DECL_ACC(i) float4 a##i = {0.f, 0.f, 0.f, 0.f};
    ROWS16(DECL_ACC)
#undef DECL_ACC

    float4 nss = {0.f, 0.f, 0.f, 0.f};            // fallback: ||n_c||^2 on the fly
    const float4* nT4 = (const float4*)nT;        // nT4[k*256 + t] = n[k][4t..4t+3]
    const float4* nd4 = (const float4*)nodes;     // nd4[c*64 + k4]  = n[c][4k..4k+3]

    if constexpr (USE_NT) {
        for (int k4 = 0; k4 < 64; ++k4) {
            float4 nv0 = nT4[(k4*4 + 0) * 256 + tid];
            float4 nv1 = nT4[(k4*4 + 1) * 256 + tid];
            float4 nv2 = nT4[(k4*4 + 2) * 256 + tid];
            float4 nv3 = nT4[(k4*4 + 3) * 256 + tid];
#define RNT(i) { float4 zv = zl4[(i) * 64 + k4];                                   \
            a##i.x = fmaf(zv.x, nv0.x, a##i.x); a##i.y = fmaf(zv.x, nv0.y, a##i.y); \
            a##i.z = fmaf(zv.x, nv0.z, a##i.z); a##i.w = fmaf(zv.x, nv0.w, a##i.w); \
            a##i.x = fmaf(zv.y, nv1.x, a##i.x); a##i.y = fmaf(zv.y, nv1.y, a##i.y); \
            a##i.z = fmaf(zv.y, nv1.z, a##i.z); a##i.w = fmaf(zv.y, nv1.w, a##i.w); \
            a##i.x = fmaf(zv.z, nv2.x, a##i.x); a##i.y = fmaf(zv.z, nv2.y, a##i.y); \
            a##i.z = fmaf(zv.z, nv2.z, a##i.z); a##i.w = fmaf(zv.z, nv2.w, a##i.w); \
            a##i.x = fmaf(zv.w, nv3.x, a##i.x); a##i.y = fmaf(zv.w, nv3.y, a##i.y); \
            a##i.z = fmaf(zv.w, nv3.z, a##i.z); a##i.w = fmaf(zv.w, nv3.w, a##i.w); }
            ROWS16(RNT)
#undef RNT
        }
    } else {
        for (int k4 = 0; k4 < 64; ++k4) {
            float4 c0 = nd4[(4*tid + 0) * 64 + k4];
            float4 c1 = nd4[(4*tid + 1) * 64 + k4];
            float4 c2 = nd4[(4*tid + 2) * 64 + k4];
            float4 c3 = nd4[(4*tid + 3) * 64 + k4];
            nss.x += c0.x*c0.x + c0.y*c0.y + c0.z*c0.z + c0.w*c0.w;
            nss.y += c1.x*c1.x + c1.y*c1.y + c1.z*c1.z + c1.w*c1.w;
            nss.z += c2.x*c2.x + c2.y*c2.y + c2.z*c2.z + c2.w*c2.w;
            nss.w += c3.x*c3.x + c3.y*c3.y + c3.z*c3.z + c3.w*c3.w;
#define RFB(i) { float4 zv = zl4[(i) * 64 + k4];                                              \
            a##i.x = fmaf(zv.x, c0.x, fmaf(zv.y, c0.y, fmaf(zv.z, c0.z, fmaf(zv.w, c0.w, a##i.x)))); \
            a##i.y = fmaf(zv.x, c1.x, fmaf(zv.y, c1.y, fmaf(zv.z, c1.z, fmaf(zv.w, c1.w, a##i.y)))); \
            a##i.z = fmaf(zv.x, c2.x, fmaf(zv.y, c2.y, fmaf(zv.z, c2.z, fmaf(zv.w, c2.w, a##i.z)))); \
            a##i.w = fmaf(zv.x, c3.x, fmaf(zv.y, c3.y, fmaf(zv.z, c3.z, fmaf(zv.w, c3.w, a##i.w)))); }
            ROWS16(RFB)
#undef RFB
        }
    }

    // ---- epilogue: dist -> q (in place), per-row q-sum + fp32 argmin ----
    float4 nsq_loc;
    if constexpr (USE_NT) nsq_loc = ((const float4*)nsq)[tid];
    else                  nsq_loc = nss;

#define EPI(i) { float zq = zsq_s[i]; unsigned long long mn = ~0ULL;        \
        a##i.x = qcomp(zq, a##i.x, nsq_loc.x, mn, 4*tid + 0);               \
        a##i.y = qcomp(zq, a##i.y, nsq_loc.y, mn, 4*tid + 1);               \
        a##i.z = qcomp(zq, a##i.z, nsq_loc.z, mn, 4*tid + 2);               \
        a##i.w = qcomp(zq, a##i.w, nsq_loc.w, mn, 4*tid + 3);               \
        float qs = a##i.x + a##i.y + a##i.z + a##i.w;                       \
        _Pragma("unroll")                                                   \
        for (int mm = 32; mm; mm >>= 1) {                                   \
            qs += __shfl_xor(qs, mm, 64);                                   \
            unsigned long long o1 = __shfl_xor(mn, mm, 64);                 \
            mn = o1 < mn ? o1 : mn;                                         \
        }                                                                   \
        if (lane == 0) { qred[i][wave] = qs; mred[i][wave] = mn; } }
    ROWS16(EPI)
#undef EPI
    __syncthreads();

    if (tid < RPB) {
        int r = tid;
        float qs = qred[r][0] + qred[r][1] + qred[r][2] + qred[r][3];
        unsigned long long mn1 = mred[r][0];
        mn1 = mred[r][1] < mn1 ? mred[r][1] : mn1;
        mn1 = mred[r][2] < mn1 ? mred[r][2] : mn1;
        mn1 = mred[r][3] < mn1 ? mred[r][3] : mn1;
        float dmin = __uint_as_float((unsigned)(mn1 >> 32));
        dmin2_s[r] = dmin * dmin;
        qinv_s[r]  = 1.f / qs;
    }
    __syncthreads();

    // ---- candidate gather (margin around fp32 min d2) + q writeback ----
#define GC(QU, COL, LIM, RI) { float dr = 1.f / (QU) - 1.f;                 \
        if (dr * dr < (LIM)) { int sl = atomicAdd(&cnt_s[RI], 1);           \
            if (sl < NCAND) cand_s[RI][sl] = (COL); } }
#define GTH(i) { float lim = dmin2_s[i] + MARGIN;                           \
        GC(a##i.x, 4*tid + 0, lim, i) GC(a##i.y, 4*tid + 1, lim, i)         \
        GC(a##i.z, 4*tid + 2, lim, i) GC(a##i.w, 4*tid + 3, lim, i) }
    ROWS16(GTH)
#undef GTH
#undef GC

    float4* q4 = (float4*)(out + OFF_Q + (size_t)row0 * G_);
#define WRQ(i) { float qi = qinv_s[i]; float4 v;                            \
        v.x = a##i.x * qi; v.y = a##i.y * qi;                               \
        v.z = a##i.z * qi; v.w = a##i.w * qi;                               \
        q4[(i) * 256 + tid] = v; }
    ROWS16(WRQ)
#undef WRQ
    __syncthreads();

    // ---- f64 re-rank of the candidate set (np-f64 reference emulation) ----
    // wz64 = f64(z)*f64(tw32)*f64(mask); compare s_c = nsq_c - 2*dot_c (zsq common);
    // tie -> lowest index. 16 threads per row.
    {
        const int r = tid >> 4;          // 0..15
        const int s = tid & 15;
        const int cnt = cnt_s[r] < NCAND ? cnt_s[r] : NCAND;
        const int row = row0 + r;
        const double w64 = (double)tw_s[r] * (double)mk_s[r];
        const float* zp = z + (size_t)row * D_;
        double bs = 1e300; int bc = 0x7FFFFFFF;
        for (int i = s; i < cnt; i += 16) {
            const int c = cand_s[r][i];
            const float* nc = nodes + (size_t)c * D_;
            double dot = 0.0, nsqd = 0.0;
            for (int k = 0; k < D_; ++k) {
                double zw = (double)zp[k] * w64;
                double nv = (double)nc[k];
                dot  = fma(zw, nv, dot);
                nsqd = fma(nv, nv, nsqd);
            }
            double sc = nsqd - 2.0 * dot;
            if (sc < bs || (sc == bs && c < bc)) { bs = sc; bc = c; }
        }
        #pragma unroll
        for (int mm = 1; mm < 16; mm <<= 1) {
            double os = __shfl_xor(bs, mm, 64);
            int    oc = __shfl_xor(bc, mm, 64);
            if (os < bs || (os == bs && oc < bc)) { bs = os; bc = oc; }
        }
        if (s == 0) {
            bmu_s[r] = bc;
            out[OFF_BMU + row]       = (float)bc;
            out[OFF_KC + 2*row]      = (float)(bc >> 5);
            out[OFF_KC + 2*row + 1]  = (float)(bc & 31);
        }
    }
    __syncthreads();

    // ---- som_z = z + 0.1*(nodes[bmu] - z)*mask ----
    const float4* zr4 = (const float4*)(z + (size_t)row0 * D_);
    float4* so4 = (float4*)(out + OFF_SOMZ + (size_t)row0 * D_);
    #pragma unroll
    for (int i = 0; i < 4; ++i) {
        int p  = i * 256 + tid;
        int r  = p >> 6;
        int k4 = p & 63;
        float4 zv = zr4[p];
        float4 nn = ((const float4*)(nodes + (size_t)bmu_s[r] * D_))[k4];
        float m = 0.1f * mk_s[r];
        float4 o;
        o.x = zv.x + m * (nn.x - zv.x);
        o.y = zv.y + m * (nn.y - zv.y);
        o.z = zv.z + m * (nn.z - zv.z);
        o.w = zv.w + m * (nn.w - zv.w);
        so4[p] = o;
    }
}

extern "C" void kernel_launch(void* const* d_in, const int* in_sizes, int n_in,
                              void* d_out, int out_size, void* d_ws, size_t ws_size,
                              hipStream_t stream) {
    const float* z     = (const float*)d_in[0];
    const float* mask  = (const float*)d_in[1];
    const float* nodes = (const float*)d_in[2];
    float* out = (float*)d_out;

    const size_t need = (size_t)(D_ * G_ + G_) * sizeof(float);  // nT + nsq (~1.05 MB)
    if (ws_size >= need) {
        float* nT  = (float*)d_ws;
        float* nsq = nT + (size_t)D_ * G_;
        prep_nodes<<<G_, 256, 0, stream>>>(nodes, nT, nsq);
        som_main<true><<<BT_ / RPB, 256, 0, stream>>>(z, mask, nodes, nT, nsq, out);
    } else {
        som_main<false><<<BT_ / RPB, 256, 0, stream>>>(z, mask, nodes, nullptr, nullptr, out);
    }
}